// Round 1
// baseline (4825.903 us; speedup 1.0000x reference)
//
#include <hip/hip_runtime.h>
#include <math.h>

#define TSEQ 256
#define CEMB 384
#define QKV_LD 1152

// ---------------------------------------------------------------------------
// GEMM: C[m,n] = sum_k A[m,k]*W[k,n] + bias[n]
// BM=BN=128, BK=16, 256 threads, 8x8 micro-tile. fp32.
// M (grid.y*128) , N (grid.x*128), K all assumed divisible by tile dims.
// lda = row stride of A (elements). ldc = N.
// ---------------------------------------------------------------------------
__global__ __launch_bounds__(256) void gemm_bias_kernel(
    const float* __restrict__ A, const float* __restrict__ W,
    const float* __restrict__ bias, float* __restrict__ C,
    int N, int K, int lda)
{
    __shared__ float As[16][132];   // transposed A tile, +4 pad keeps float4 align
    __shared__ float Bs[16][128];

    const int tid = threadIdx.x;
    const int tx = tid & 15;        // n-direction micro index
    const int ty = tid >> 4;        // m-direction micro index
    const int m0 = blockIdx.y * 128;
    const int n0 = blockIdx.x * 128;

    const int arow = tid >> 1;          // 0..127
    const int acol = (tid & 1) * 8;     // 0 or 8
    const int brow = tid >> 4;          // 0..15
    const int bcol = (tid & 15) * 8;    // 0..120

    float acc[8][8];
    #pragma unroll
    for (int i = 0; i < 8; ++i)
        #pragma unroll
        for (int j = 0; j < 8; ++j) acc[i][j] = 0.f;

    for (int k0 = 0; k0 < K; k0 += 16) {
        const float* ap = A + (size_t)(m0 + arow) * lda + k0 + acol;
        float4 a0 = *(const float4*)(ap);
        float4 a1 = *(const float4*)(ap + 4);
        const float* wp = W + (size_t)(k0 + brow) * N + n0 + bcol;
        float4 b0 = *(const float4*)(wp);
        float4 b1 = *(const float4*)(wp + 4);

        __syncthreads();   // previous tile's compute done before overwrite
        As[acol + 0][arow] = a0.x;
        As[acol + 1][arow] = a0.y;
        As[acol + 2][arow] = a0.z;
        As[acol + 3][arow] = a0.w;
        As[acol + 4][arow] = a1.x;
        As[acol + 5][arow] = a1.y;
        As[acol + 6][arow] = a1.z;
        As[acol + 7][arow] = a1.w;
        *(float4*)&Bs[brow][bcol]     = b0;
        *(float4*)&Bs[brow][bcol + 4] = b1;
        __syncthreads();

        #pragma unroll
        for (int k = 0; k < 16; ++k) {
            float4 av0 = *(const float4*)&As[k][ty * 8];
            float4 av1 = *(const float4*)&As[k][ty * 8 + 4];
            float4 bv0 = *(const float4*)&Bs[k][tx * 8];
            float4 bv1 = *(const float4*)&Bs[k][tx * 8 + 4];
            float a[8] = {av0.x, av0.y, av0.z, av0.w, av1.x, av1.y, av1.z, av1.w};
            float b[8] = {bv0.x, bv0.y, bv0.z, bv0.w, bv1.x, bv1.y, bv1.z, bv1.w};
            #pragma unroll
            for (int i = 0; i < 8; ++i)
                #pragma unroll
                for (int j = 0; j < 8; ++j)
                    acc[i][j] += a[i] * b[j];
        }
    }

    float4 bb0 = *(const float4*)(bias + n0 + tx * 8);
    float4 bb1 = *(const float4*)(bias + n0 + tx * 8 + 4);
    float bv[8] = {bb0.x, bb0.y, bb0.z, bb0.w, bb1.x, bb1.y, bb1.z, bb1.w};

    #pragma unroll
    for (int i = 0; i < 8; ++i) {
        size_t row = (size_t)(m0 + ty * 8 + i);
        float* cp = C + row * N + n0 + tx * 8;
        float4 o0 = make_float4(acc[i][0] + bv[0], acc[i][1] + bv[1],
                                acc[i][2] + bv[2], acc[i][3] + bv[3]);
        float4 o1 = make_float4(acc[i][4] + bv[4], acc[i][5] + bv[5],
                                acc[i][6] + bv[6], acc[i][7] + bv[7]);
        *(float4*)(cp)     = o0;
        *(float4*)(cp + 4) = o1;
    }
}

// ---------------------------------------------------------------------------
// Attention: one block per (b,t). qkv row layout: [q(384) | k(384) | v(384)].
// Writes attention output IN-PLACE into the q slot of row (b,t) — safe because
// q[b,t] is only ever read by this block.
// ---------------------------------------------------------------------------
__global__ __launch_bounds__(256) void attn_kernel(float* __restrict__ qkv)
{
    const int t = blockIdx.x;
    const int b = blockIdx.y;
    const int tid = threadIdx.x;
    const int lane = tid & 63;
    const int wave = tid >> 6;

    __shared__ float sc[TSEQ];
    __shared__ float red[4];

    float* base = qkv + (size_t)b * TSEQ * QKV_LD;
    float* qrow = base + (size_t)t * QKV_LD;

    // q in registers: lane holds channels lane, lane+64, ..., lane+320
    float q[6];
    #pragma unroll
    for (int j = 0; j < 6; ++j) q[j] = qrow[lane + 64 * j];

    const float scale = 0.051031036307982884f;  // 1/sqrt(384)

    // phase 1: scores s = 0..t, one wave per score, coalesced k reads
    for (int s = wave; s <= t; s += 4) {
        const float* krow = base + (size_t)s * QKV_LD + CEMB;
        float p = 0.f;
        #pragma unroll
        for (int j = 0; j < 6; ++j) p += q[j] * krow[lane + 64 * j];
        #pragma unroll
        for (int off = 32; off >= 1; off >>= 1) p += __shfl_xor(p, off);
        if (lane == 0) sc[s] = p * scale;
    }
    __syncthreads();

    // softmax over sc[0..t]
    float v = (tid <= t) ? sc[tid] : -INFINITY;
    float m = v;
    #pragma unroll
    for (int off = 32; off >= 1; off >>= 1) m = fmaxf(m, __shfl_xor(m, off));
    if (lane == 0) red[wave] = m;
    __syncthreads();
    m = fmaxf(fmaxf(red[0], red[1]), fmaxf(red[2], red[3]));
    __syncthreads();   // all reads of red done before reuse

    float e = (tid <= t) ? __expf(v - m) : 0.f;
    float ssum = e;
    #pragma unroll
    for (int off = 32; off >= 1; off >>= 1) ssum += __shfl_xor(ssum, off);
    if (lane == 0) red[wave] = ssum;
    __syncthreads();
    float inv = 1.f / (red[0] + red[1] + red[2] + red[3]);

    sc[tid] = e * inv;   // probabilities (0 for tid > t)
    __syncthreads();

    // phase 2: out[c] = sum_s p[s] * v[b,s,c]; coalesced across c
    for (int c = tid; c < CEMB; c += 256) {
        float accv = 0.f;
        const float* vptr = base + 2 * CEMB + c;
        #pragma unroll 4
        for (int s = 0; s <= t; ++s) accv += sc[s] * vptr[(size_t)s * QKV_LD];
        qrow[c] = accv;   // in-place into q slot
    }
}

// ---------------------------------------------------------------------------
extern "C" void kernel_launch(void* const* d_in, const int* in_sizes, int n_in,
                              void* d_out, int out_size, void* d_ws, size_t ws_size,
                              hipStream_t stream)
{
    const float* x      = (const float*)d_in[0];
    const float* W_qkv  = (const float*)d_in[1];
    const float* b_qkv  = (const float*)d_in[2];
    const float* W_proj = (const float*)d_in[3];
    const float* b_proj = (const float*)d_in[4];
    float* out = (float*)d_out;
    float* qkv = (float*)d_ws;

    const int Btot = 512;
    const size_t per_batch_bytes = (size_t)TSEQ * QKV_LD * sizeof(float); // 1.125 MiB

    int chunk = (int)(ws_size / per_batch_bytes);
    if (chunk > Btot) chunk = Btot;
    if (chunk < 1) chunk = 1;

    for (int b0 = 0; b0 < Btot; b0 += chunk) {
        int cb = (chunk < Btot - b0) ? chunk : (Btot - b0);
        int Mc = cb * TSEQ;   // multiple of 256 -> divisible by 128

        // QKV GEMM: [Mc,384] x [384,1152] + bias -> qkv (ws)
        gemm_bias_kernel<<<dim3(QKV_LD / 128, Mc / 128), 256, 0, stream>>>(
            x + (size_t)b0 * TSEQ * CEMB, W_qkv, b_qkv, qkv, QKV_LD, CEMB, CEMB);

        // attention (in-place output into q slots)
        attn_kernel<<<dim3(TSEQ, cb), 256, 0, stream>>>(qkv);

        // proj GEMM: [Mc,384](stride 1152, q-slots) x [384,384] + bias -> out
        gemm_bias_kernel<<<dim3(CEMB / 128, Mc / 128), 256, 0, stream>>>(
            qkv, W_proj, b_proj, out + (size_t)b0 * TSEQ * CEMB, CEMB, CEMB, QKV_LD);
    }
}

// Round 2
// 2705.497 us; speedup vs baseline: 1.7837x; 1.7837x over previous
//
#include <hip/hip_runtime.h>
#include <math.h>

#define TSEQ 256
#define CEMB 384
#define QKV_LD 1152

typedef short short8 __attribute__((ext_vector_type(8)));
typedef float f32x4 __attribute__((ext_vector_type(4)));

// fp32 -> bf16 bits, round-to-nearest-even (values here are finite, no NaN).
static __device__ __forceinline__ short f2bf(float f) {
    union { float f; unsigned u; } a;
    a.f = f;
    unsigned u = a.u + 0x7fffu + ((a.u >> 16) & 1u);
    return (short)(u >> 16);
}

// ---------------------------------------------------------------------------
// fp32 GEMM: C[m,n] = sum_k A[m,k]*W[k,n] + bias[n]  (unchanged from R1)
// ---------------------------------------------------------------------------
__global__ __launch_bounds__(256) void gemm_bias_kernel(
    const float* __restrict__ A, const float* __restrict__ W,
    const float* __restrict__ bias, float* __restrict__ C,
    int N, int K, int lda)
{
    __shared__ float As[16][132];
    __shared__ float Bs[16][128];

    const int tid = threadIdx.x;
    const int tx = tid & 15;
    const int ty = tid >> 4;
    const int m0 = blockIdx.y * 128;
    const int n0 = blockIdx.x * 128;

    const int arow = tid >> 1;
    const int acol = (tid & 1) * 8;
    const int brow = tid >> 4;
    const int bcol = (tid & 15) * 8;

    float acc[8][8];
    #pragma unroll
    for (int i = 0; i < 8; ++i)
        #pragma unroll
        for (int j = 0; j < 8; ++j) acc[i][j] = 0.f;

    for (int k0 = 0; k0 < K; k0 += 16) {
        const float* ap = A + (size_t)(m0 + arow) * lda + k0 + acol;
        float4 a0 = *(const float4*)(ap);
        float4 a1 = *(const float4*)(ap + 4);
        const float* wp = W + (size_t)(k0 + brow) * N + n0 + bcol;
        float4 b0 = *(const float4*)(wp);
        float4 b1 = *(const float4*)(wp + 4);

        __syncthreads();
        As[acol + 0][arow] = a0.x;
        As[acol + 1][arow] = a0.y;
        As[acol + 2][arow] = a0.z;
        As[acol + 3][arow] = a0.w;
        As[acol + 4][arow] = a1.x;
        As[acol + 5][arow] = a1.y;
        As[acol + 6][arow] = a1.z;
        As[acol + 7][arow] = a1.w;
        *(float4*)&Bs[brow][bcol]     = b0;
        *(float4*)&Bs[brow][bcol + 4] = b1;
        __syncthreads();

        #pragma unroll
        for (int k = 0; k < 16; ++k) {
            float4 av0 = *(const float4*)&As[k][ty * 8];
            float4 av1 = *(const float4*)&As[k][ty * 8 + 4];
            float4 bv0 = *(const float4*)&Bs[k][tx * 8];
            float4 bv1 = *(const float4*)&Bs[k][tx * 8 + 4];
            float a[8] = {av0.x, av0.y, av0.z, av0.w, av1.x, av1.y, av1.z, av1.w};
            float b[8] = {bv0.x, bv0.y, bv0.z, bv0.w, bv1.x, bv1.y, bv1.z, bv1.w};
            #pragma unroll
            for (int i = 0; i < 8; ++i)
                #pragma unroll
                for (int j = 0; j < 8; ++j)
                    acc[i][j] += a[i] * b[j];
        }
    }

    float4 bb0 = *(const float4*)(bias + n0 + tx * 8);
    float4 bb1 = *(const float4*)(bias + n0 + tx * 8 + 4);
    float bv[8] = {bb0.x, bb0.y, bb0.z, bb0.w, bb1.x, bb1.y, bb1.z, bb1.w};

    #pragma unroll
    for (int i = 0; i < 8; ++i) {
        size_t row = (size_t)(m0 + ty * 8 + i);
        float* cp = C + row * N + n0 + tx * 8;
        float4 o0 = make_float4(acc[i][0] + bv[0], acc[i][1] + bv[1],
                                acc[i][2] + bv[2], acc[i][3] + bv[3]);
        float4 o1 = make_float4(acc[i][4] + bv[4], acc[i][5] + bv[5],
                                acc[i][6] + bv[6], acc[i][7] + bv[7]);
        *(float4*)(cp)     = o0;
        *(float4*)(cp + 4) = o1;
    }
}

// ---------------------------------------------------------------------------
// Cast k/v slots of fp32 qkv into bf16: Kb[b][t][c] row-major, Vt[b][c][t]
// transposed. Block handles 32 t-rows of one batch.
// ---------------------------------------------------------------------------
__global__ __launch_bounds__(256) void cast_kv_kernel(
    const float* __restrict__ qkv, unsigned short* __restrict__ Kb,
    unsigned short* __restrict__ Vt)
{
    const int b  = blockIdx.y;
    const int t0 = blockIdx.x * 32;
    const int tid = threadIdx.x;

    // K: 32 rows x 384 ch = 1536 items of 8 channels
    for (int i = tid; i < 1536; i += 256) {
        int t  = i / 48;
        int cc = (i % 48) * 8;
        const float* src = qkv + ((size_t)b * TSEQ + t0 + t) * QKV_LD + CEMB + cc;
        float4 x0 = *(const float4*)(src);
        float4 x1 = *(const float4*)(src + 4);
        short8 o;
        o[0] = f2bf(x0.x); o[1] = f2bf(x0.y); o[2] = f2bf(x0.z); o[3] = f2bf(x0.w);
        o[4] = f2bf(x1.x); o[5] = f2bf(x1.y); o[6] = f2bf(x1.z); o[7] = f2bf(x1.w);
        *(short8*)(Kb + ((size_t)b * TSEQ + t0 + t) * CEMB + cc) = o;
    }

    // V transpose: item = (channel c, t-group of 8)
    for (int i = tid; i < 1536; i += 256) {
        int c  = i % 384;
        int tg = (i / 384) * 8;
        const float* src = qkv + ((size_t)b * TSEQ + t0 + tg) * QKV_LD + 2 * CEMB + c;
        short8 o;
        #pragma unroll
        for (int j = 0; j < 8; ++j)
            o[j] = f2bf(src[(size_t)j * QKV_LD]);
        *(short8*)(Vt + ((size_t)b * CEMB + c) * TSEQ + t0 + tg) = o;
    }
}

// ---------------------------------------------------------------------------
// Flash attention, bf16 MFMA 16x16x32. One wave = one 16-row Q strip.
// Block = 4 waves (4 strips = 64 q rows), grid = 4 * cb blocks.
// Q read fp32 from qkv (converted in-kernel); K from Kb; V from Vt (transposed
// so B-fragments are contiguous 16B). Output fp32 into qkv q-slot.
// MFMA layouts (m89/m120-verified): A[m=lane&15][k=quad*8+j],
// B[k=quad*8+j][n=lane&15], C/D col=lane&15, row=quad*4+reg.
// ---------------------------------------------------------------------------
__global__ __launch_bounds__(256, 2) void attn_mfma_kernel(
    float* __restrict__ qkv, const unsigned short* __restrict__ Kb,
    const unsigned short* __restrict__ Vt, int swizzle)
{
    int bid = blockIdx.x;
    int b, g;
    if (swizzle) {   // keep one batch's 4 blocks on one XCD (round-robin assumption)
        g = (bid >> 3) & 3;
        b = ((bid >> 5) << 3) | (bid & 7);
    } else {
        b = bid >> 2;
        g = bid & 3;
    }
    const int wave = threadIdx.x >> 6;
    const int lane = threadIdx.x & 63;
    const int quad = lane >> 4;
    const int l16  = lane & 15;
    const int Q0   = g * 64 + wave * 16;   // this wave's first q row

    __shared__ unsigned short Pbuf[4][16 * 32];
    unsigned short* Pw = &Pbuf[wave][0];

    const float scale = 0.051031036307982884f;  // 1/sqrt(384)

    // ---- load Q fragments (A-operand), converting fp32 -> bf16 ----
    const float* qbase = qkv + ((size_t)b * TSEQ + Q0) * QKV_LD;
    short8 qf[12];
    #pragma unroll
    for (int f = 0; f < 12; ++f) {
        const float* qp = qbase + (size_t)l16 * QKV_LD + f * 32 + quad * 8;
        float4 x0 = *(const float4*)(qp);
        float4 x1 = *(const float4*)(qp + 4);
        short8 o;
        o[0] = f2bf(x0.x); o[1] = f2bf(x0.y); o[2] = f2bf(x0.z); o[3] = f2bf(x0.w);
        o[4] = f2bf(x1.x); o[5] = f2bf(x1.y); o[6] = f2bf(x1.z); o[7] = f2bf(x1.w);
        qf[f] = o;
    }

    f32x4 acc[24];
    #pragma unroll
    for (int ct = 0; ct < 24; ++ct) acc[ct] = (f32x4){0.f, 0.f, 0.f, 0.f};
    float m_run[4] = {-1e30f, -1e30f, -1e30f, -1e30f};
    float l_run[4] = {0.f, 0.f, 0.f, 0.f};

    const unsigned short* kB = Kb + (size_t)b * TSEQ * CEMB;
    const unsigned short* vB = Vt + (size_t)b * CEMB * TSEQ;

    const int nkt = (Q0 + 16 + 31) >> 5;   // k-tiles of 32 covering k <= Q0+15

    for (int kt = 0; kt < nkt; ++kt) {
        const int k0 = kt * 32;

        // ---- S strip: two 16x16 halves, K accumulated over 12 frags ----
        f32x4 s0 = (f32x4){0.f, 0.f, 0.f, 0.f};
        f32x4 s1 = (f32x4){0.f, 0.f, 0.f, 0.f};
        const short8* kp0 = (const short8*)(kB + (size_t)(k0 + l16) * CEMB + quad * 8);
        const short8* kp1 = (const short8*)(kB + (size_t)(k0 + 16 + l16) * CEMB + quad * 8);
        #pragma unroll
        for (int f = 0; f < 12; ++f) {
            short8 b0 = kp0[f * 4];   // f*32 shorts = f*4 short8
            short8 b1 = kp1[f * 4];
            s0 = __builtin_amdgcn_mfma_f32_16x16x32_bf16(qf[f], b0, s0, 0, 0, 0);
            s1 = __builtin_amdgcn_mfma_f32_16x16x32_bf16(qf[f], b1, s1, 0, 0, 0);
        }

        // ---- scale + causal mask ----
        float sv0[4], sv1[4], mt[4];
        const bool need_mask = (k0 + 31 > Q0);   // wave-uniform
        #pragma unroll
        for (int r = 0; r < 4; ++r) {
            const int qrow = Q0 + quad * 4 + r;
            float a = s0[r] * scale;
            float c = s1[r] * scale;
            if (need_mask) {
                if (k0 + l16 > qrow)      a = -1e30f;
                if (k0 + 16 + l16 > qrow) c = -1e30f;
            }
            sv0[r] = a; sv1[r] = c;
            mt[r] = fmaxf(a, c);
        }
        // row-max across the 16 lanes of each quad
        #pragma unroll
        for (int off = 1; off <= 8; off <<= 1)
            #pragma unroll
            for (int r = 0; r < 4; ++r)
                mt[r] = fmaxf(mt[r], __shfl_xor(mt[r], off));

        float alpha[4], p0[4], p1[4], rs[4];
        #pragma unroll
        for (int r = 0; r < 4; ++r) {
            float mn = fmaxf(m_run[r], mt[r]);
            alpha[r] = __expf(m_run[r] - mn);
            m_run[r] = mn;
            p0[r] = __expf(sv0[r] - mn);
            p1[r] = __expf(sv1[r] - mn);
            rs[r] = p0[r] + p1[r];
        }
        #pragma unroll
        for (int off = 1; off <= 8; off <<= 1)
            #pragma unroll
            for (int r = 0; r < 4; ++r)
                rs[r] += __shfl_xor(rs[r], off);
        #pragma unroll
        for (int r = 0; r < 4; ++r)
            l_run[r] = l_run[r] * alpha[r] + rs[r];

        // ---- P (C-layout) -> LDS -> A-layout fragment ----
        #pragma unroll
        for (int r = 0; r < 4; ++r) {
            const int row = quad * 4 + r;
            Pw[row * 32 + l16]      = (unsigned short)f2bf(p0[r]);
            Pw[row * 32 + 16 + l16] = (unsigned short)f2bf(p1[r]);
        }
        __asm__ __volatile__("s_waitcnt lgkmcnt(0)" ::: "memory");
        short8 pf = *(const short8*)(Pw + (size_t)l16 * 32 + quad * 8);

        // ---- O = O*alpha + P·V over 24 channel tiles ----
        const short8* vp = (const short8*)(vB + (size_t)l16 * TSEQ + k0 + quad * 8);
        #pragma unroll
        for (int ct = 0; ct < 24; ++ct) {
            short8 vf = vp[ct * 16 * TSEQ / 8];   // ct*512 short8
            f32x4 a = acc[ct];
            #pragma unroll
            for (int r = 0; r < 4; ++r) a[r] *= alpha[r];
            acc[ct] = __builtin_amdgcn_mfma_f32_16x16x32_bf16(pf, vf, a, 0, 0, 0);
        }
    }

    // ---- epilogue: normalize, write fp32 into q slot ----
    float inv[4];
    #pragma unroll
    for (int r = 0; r < 4; ++r) inv[r] = 1.f / l_run[r];
    #pragma unroll
    for (int ct = 0; ct < 24; ++ct) {
        #pragma unroll
        for (int r = 0; r < 4; ++r) {
            float* op = qkv + ((size_t)b * TSEQ + Q0 + quad * 4 + r) * QKV_LD
                        + ct * 16 + l16;
            *op = acc[ct][r] * inv[r];
        }
    }
}

// ---------------------------------------------------------------------------
extern "C" void kernel_launch(void* const* d_in, const int* in_sizes, int n_in,
                              void* d_out, int out_size, void* d_ws, size_t ws_size,
                              hipStream_t stream)
{
    const float* x      = (const float*)d_in[0];
    const float* W_qkv  = (const float*)d_in[1];
    const float* b_qkv  = (const float*)d_in[2];
    const float* W_proj = (const float*)d_in[3];
    const float* b_proj = (const float*)d_in[4];
    float* out = (float*)d_out;

    const int Btot = 512;
    // per-batch ws: qkv fp32 (1152*256*4) + Kb bf16 (384*256*2) + Vt bf16
    const size_t qkv_pb = (size_t)TSEQ * QKV_LD * sizeof(float);      // 1179648
    const size_t kb_pb  = (size_t)TSEQ * CEMB * sizeof(short);        // 196608
    const size_t per_batch = qkv_pb + 2 * kb_pb;                      // 1572864

    int chunk = (int)(ws_size / per_batch);
    if (chunk > Btot) chunk = Btot;
    if (chunk < 1) chunk = 1;
    if (chunk >= 8) chunk -= chunk % 8;   // enable XCD swizzle

    float* qkv = (float*)d_ws;
    unsigned short* Kb = (unsigned short*)((char*)d_ws + qkv_pb * chunk);
    unsigned short* Vt = (unsigned short*)((char*)d_ws + (qkv_pb + kb_pb) * chunk);

    for (int b0 = 0; b0 < Btot; b0 += chunk) {
        int cb = (chunk < Btot - b0) ? chunk : (Btot - b0);
        int Mc = cb * TSEQ;

        // QKV GEMM (fp32): [Mc,384] x [384,1152] + bias -> qkv
        gemm_bias_kernel<<<dim3(QKV_LD / 128, Mc / 128), 256, 0, stream>>>(
            x + (size_t)b0 * TSEQ * CEMB, W_qkv, b_qkv, qkv, QKV_LD, CEMB, CEMB);

        // cast k/v to bf16 (+ V transpose)
        cast_kv_kernel<<<dim3(8, cb), 256, 0, stream>>>(qkv, Kb, Vt);

        // flash attention (bf16 MFMA), in-place output into q slots
        int swz = (cb % 8 == 0) ? 1 : 0;
        attn_mfma_kernel<<<dim3(4 * cb), 256, 0, stream>>>(qkv, Kb, Vt, swz);

        // proj GEMM (fp32): [Mc,384](q-slots, lda=1152) x [384,384] + bias
        gemm_bias_kernel<<<dim3(CEMB / 128, Mc / 128), 256, 0, stream>>>(
            qkv, W_proj, b_proj, out + (size_t)b0 * TSEQ * CEMB, CEMB, CEMB, QKV_LD);
    }
}